// Round 2
// baseline (19546.309 us; speedup 1.0000x reference)
//
#include <hip/hip_runtime.h>
#include <math.h>

// ---------------------------------------------------------------------------
// R13: R12's latency-tax removal, with the store path fixed to compile.
//   1) Monotonic flag caching + wave-level polls: a satisfied poll is ~4 VALU
//      ops (was: 1 LLC atomic load ~700cy + __syncthreads). Each wave polls
//      independently; the stage/epilogue barriers already order LDS reuse.
//   2) Upstream hin register-prefetch (stages 1-3): gated on the cached
//      upstream flag >= t+2 (upstream leads by ring depth in steady state);
//      loads issued before the epilogue drain, consumed next iteration as a
//      pure LDS write. Backpressure lanes still poll when prefetched.
//   3) Coalesced ring stores WITHOUT 128-bit asm inputs (LLVM can't take
//      float4 "v" inputs): epilogue stages h into a [32][U+4] LDS tile, then
//      each thread issues 4B agent-scope atomic stores (the R3/R5-proven LLC
//      transport) with a column-major mapping i=k*256+tid -> each store
//      instruction's 64 lanes cover 256 contiguous bytes. R11's mapping had
//      1KB lane stride = 64 transactions/instr (WRITE_SIZE showed 1.42x
//      write amplification).
//   4) tanhf -> __expf-based tanh (libm tanhf is ~30+ instrs).
// Transport semantics unchanged: sc0 sc1 loads read the LLC; agent-scope
// atomic stores land at the LLC; drain (vmcnt 0) + barrier before the flag
// store. Zero cache maintenance. Bounded spins kept (failure -> absmax).
// ---------------------------------------------------------------------------

__device__ __forceinline__ float sigmoidf_(float v) {
    return 1.0f / (1.0f + __expf(-v));
}
__device__ __forceinline__ float tanhf_(float v) {
    float e = __expf(2.0f * v);
    return 1.0f - 2.0f / (e + 1.0f);
}

// src[(g*H+u)*J + j] -> dst[(u*3+g)*J + j]
__global__ void prep_k(const float* __restrict__ src, float* __restrict__ dst,
                       int H, int J) {
    int idx = blockIdx.x * 256 + threadIdx.x;
    int total = 3 * H * J;
    if (idx < total) {
        int g = idx / (H * J);
        int rem = idx - g * H * J;
        int u = rem / J;
        int j = rem - u * J;
        dst[(u * 3 + g) * J + j] = src[(g * H + u) * J + j];
    }
}

// ---- transport primitives --------------------------------------------------

__device__ __forceinline__ void flag_st(int* p, int v) {
    __hip_atomic_store(p, v, __ATOMIC_RELAXED, __HIP_MEMORY_SCOPE_AGENT);
}
__device__ __forceinline__ int flag_ld(const int* p) {
    return __hip_atomic_load(p, __ATOMIC_RELAXED, __HIP_MEMORY_SCOPE_AGENT);
}
__device__ __forceinline__ void ex_store(float* p, float v) {
    __hip_atomic_store(p, v, __ATOMIC_RELAXED, __HIP_MEMORY_SCOPE_AGENT);
}

// Wave-level cached poll. Flags are monotonic: if the per-lane cache already
// satisfies the target, cost is a few VALU ops and no memory traffic.
// No barrier inside -- callers' stage/epilogue barriers provide ordering.
__device__ __forceinline__ void pollw(const int* p, int tgt, bool active,
                                      int& fc) {
    bool need = active && (fc < tgt);
    if (!__any(need)) return;
    int spins = 0;
    while (true) {
        if (need) { fc = flag_ld(p); need = (fc < tgt); }
        if (!__any(need)) return;
        if (++spins > 16) __builtin_amdgcn_s_sleep(1);
        if (spins > 200000) return;  // bounded: degrade to absmax diagnostic
    }
}

// ---- staging: ring -> regs -> LDS (split so prefetch can hold regs) -------

template <int J>
__device__ __forceinline__ void stage_load(float4* r, const float* src) {
    constexpr int NF4 = (32 * J) / 1024;
    #pragma unroll
    for (int k = 0; k < NF4; ++k) {
        const float* p = src + (size_t)(k * 256 + threadIdx.x) * 4;
        asm volatile("global_load_dwordx4 %0, %1, off sc0 sc1"
                     : "=v"(r[k]) : "v"(p) : "memory");
    }
}

template <int J>
__device__ __forceinline__ void stage_write(const float4* r, float* dst) {
    constexpr int NF4 = (32 * J) / 1024;
    constexpr int LJ = (J == 256) ? 8 : 7;
    #pragma unroll
    for (int k = 0; k < NF4; ++k) {
        int i = (k * 256 + threadIdx.x) * 4;
        int b = i >> LJ;
        int j = i & (J - 1);
        *(float4*)(dst + b * (J + 4) + j) = r[k];
    }
}

template <int J>
__device__ __forceinline__ void stageX(float* dst, const float* src) {
    float4 tmp[(32 * J) / 1024];
    stage_load<J>(tmp, src);
    asm volatile("s_waitcnt vmcnt(0)" ::: "memory");
    stage_write<J>(tmp, dst);
}

template <int J>
__device__ __forceinline__ void zero32(float* dst) {
    for (int i = threadIdx.x; i < 32 * (J + 4); i += 256) dst[i] = 0.0f;
}

// Coalesced ring store: read the [32][U+4] LDS staging tile with a
// column-major thread mapping and emit 4B agent-scope stores whose 64-lane
// footprint is contiguous (2x128B lines for U=32, 4x64B segments for U=16).
template <int U, int J>
__device__ __forceinline__ void ring_store(float* hout, const float* hst) {
    constexpr int LU = (U == 32) ? 5 : 4;
    #pragma unroll
    for (int k = 0; k < (32 * U) / 256; ++k) {
        int i = k * 256 + threadIdx.x;
        int b = i >> LU;
        int c = i & (U - 1);
        ex_store(hout + b * J + c, hst[b * (U + 4) + c]);
    }
}

// acc{r,z,c} += w{R,Z,N} . h[row] for KB batch rows (row = b0 + k*(32/KB))
template <int KB, int J>
__device__ __forceinline__ void dot3(const float* __restrict__ w3,
                                     const float* __restrict__ hst, int b0,
                                     float* ar, float* az, float* ac) {
    const float4* wr = (const float4*)w3;
    const float4* wz = (const float4*)(w3 + J);
    const float4* wn = (const float4*)(w3 + 2 * J);
    const float* rows[KB];
    #pragma unroll
    for (int k = 0; k < KB; ++k) rows[k] = hst + (b0 + k * (32 / KB)) * (J + 4);
    #pragma unroll 4
    for (int j4 = 0; j4 < J / 4; ++j4) {
        float4 a = wr[j4];
        float4 c = wz[j4];
        float4 d = wn[j4];
        #pragma unroll
        for (int k = 0; k < KB; ++k) {
            float4 hv = *(const float4*)(rows[k] + j4 * 4);
            ar[k] = fmaf(hv.x, a.x, ar[k]); ar[k] = fmaf(hv.y, a.y, ar[k]);
            ar[k] = fmaf(hv.z, a.z, ar[k]); ar[k] = fmaf(hv.w, a.w, ar[k]);
            az[k] = fmaf(hv.x, c.x, az[k]); az[k] = fmaf(hv.y, c.y, az[k]);
            az[k] = fmaf(hv.z, c.z, az[k]); az[k] = fmaf(hv.w, c.w, az[k]);
            ac[k] = fmaf(hv.x, d.x, ac[k]); ac[k] = fmaf(hv.y, d.y, ac[k]);
            ac[k] = fmaf(hv.z, d.z, ac[k]); ac[k] = fmaf(hv.w, d.w, ac[k]);
        }
    }
}

__global__ __launch_bounds__(256) void gru_pipe_kernel(
    const float* __restrict__ x,
    const float* __restrict__ w_ih1,
    const float* __restrict__ b_ih1, const float* __restrict__ b_hh1,
    const float* __restrict__ b_ih2, const float* __restrict__ b_hh2,
    const float* __restrict__ b_ih3, const float* __restrict__ b_hh3,
    const float* __restrict__ b_ih4, const float* __restrict__ b_hh4,
    const float* __restrict__ wA_hh1,  // [256][3][256]
    const float* __restrict__ wA_ih2,  // [128][3][256]
    const float* __restrict__ wA_hh2,  // [128][3][128]
    const float* __restrict__ wA_ih3,  // [128][3][128]
    const float* __restrict__ wA_hh3,  // [128][3][128]
    const float* __restrict__ wA_ih4,  // [256][3][128]
    const float* __restrict__ wA_hh4,  // [256][3][256]
    const float* __restrict__ w_out, const float* __restrict__ b_out,
    int* __restrict__ flags,  // [8 bg][4 stages x 32 ints (128B line)]
    float* __restrict__ ex,   // [8 bg][98304] h rings
    float* __restrict__ out)  // [256][1024] pre-zeroed
{
    const int tid = threadIdx.x;
    const int lane = tid & 63;
    extern __shared__ float smem[];
    __shared__ float xs[32];
    __shared__ float wsum[4][4][8];

    const int bg = blockIdx.x & 7;        // batch group (32 rows)
    const int rest = blockIdx.x >> 3;
    const int s = rest >> 3;              // stage 0..3
    const int us = rest & 7;              // unit slice 0..7

    int* fb = flags + bg * 128;           // 4 lines x 32 ints
    int* arr_own = fb + s * 32;           // this stage's 8 seq numbers

    // per-lane poll assignments (every wave, lanes by lane-id)
    const int* pT = arr_own; int dT = 0; bool aT = false;
    const int* pM = arr_own; bool aM = false;
    if (lane < 8) {
        if (s > 0) { pT = fb + (s - 1) * 32 + lane; dT = 1; aT = true; }
        pM = arr_own + lane; aM = true;
    } else if (lane < 16) {
        if (s < 3) { pT = fb + (s + 1) * 32 + (lane - 8); dT = -3; aT = true; }
    }
    const bool aUp = (s > 0) && (lane < 8);
    int fcT = 0, fcM = 0;  // per-lane monotonic flag caches

    float* exb = ex + (size_t)bg * 98304;
    float* h1r = exb;            // 4 slots x 32 x 256
    float* h2r = exb + 32768;    // 4 x 32 x 128
    float* h3r = exb + 49152;
    float* h4r = exb + 65536;

    if (s == 0) {
        // ---- layer 1: in=1 scalar, H=256, 32 units/slice, KB=4 ----
        float* wlds = smem;            // [32][772]
        float* hprev = smem + 24704;   // [32][260]
        float* hst = smem + 33024;     // [32][36] epilogue staging
        {
            const float* srcw = wA_hh1 + (size_t)us * 32 * 768;
            for (int i = tid; i < 24576; i += 256) {
                int uu = i / 768, r = i - uu * 768;
                wlds[uu * 772 + r] = srcw[i];
            }
        }
        __syncthreads();
        const int ul = tid >> 3, b0 = tid & 7;
        const int u = us * 32 + ul;
        const float* wh = wlds + ul * 772;
        const float br = b_ih1[u] + b_hh1[u];
        const float bz = b_ih1[u + 256] + b_hh1[u + 256];
        const float bxn = b_ih1[u + 512];
        const float bhn = b_hh1[u + 512];
        const float wir = w_ih1[u], wiz = w_ih1[u + 256], win = w_ih1[u + 512];
        for (int t = 0; t < 1024; ++t) {
            pollw(pT, t + dT, aT, fcT);        // downstream backpressure
            if (tid < 32) xs[tid] = x[(size_t)(bg * 32 + tid) * 1024 + t];
            pollw(pM, t, aM, fcM);             // peers done t-1
            if (t > 0) stageX<256>(hprev, h1r + (size_t)((t - 1) & 3) * 8192);
            else       zero32<256>(hprev);
            __syncthreads();
            float ar[4], az[4], axn[4], ahn[4];
            #pragma unroll
            for (int k = 0; k < 4; ++k) {
                float xv = xs[b0 + 8 * k];
                ar[k] = br + xv * wir; az[k] = bz + xv * wiz;
                axn[k] = bxn + xv * win; ahn[k] = bhn;
            }
            dot3<4, 256>(wh, hprev, b0, ar, az, ahn);
            float* hout = h1r + (size_t)(t & 3) * 8192;
            #pragma unroll
            for (int k = 0; k < 4; ++k) {
                int b = b0 + 8 * k;
                float hp = hprev[b * 260 + u];
                float r = sigmoidf_(ar[k]);
                float z = sigmoidf_(az[k]);
                float n = tanhf_(axn[k] + r * ahn[k]);
                hst[b * 36 + ul] = (1.f - z) * n + z * hp;
            }
            __syncthreads();
            ring_store<32, 256>(hout + us * 32, hst);
            asm volatile("s_waitcnt vmcnt(0)" ::: "memory");  // h at LLC
            __syncthreads();
            if (tid == 0) flag_st(arr_own + us, t + 1);
        }
    } else if (s == 1) {
        // ---- layer 2: in=256, H=128, 16 units/slice, KB=2 ----
        float* wlds = smem;            // [16][388]
        float* hin = smem + 6208;      // [32][260]
        float* hprev = smem + 14528;   // [32][132]
        float* hst = smem + 18752;     // [32][20]
        {
            const float* srcw = wA_hh2 + (size_t)us * 16 * 384;
            for (int i = tid; i < 6144; i += 256) {
                int uu = i / 384, r = i - uu * 384;
                wlds[uu * 388 + r] = srcw[i];
            }
        }
        __syncthreads();
        const int ul = tid >> 4, b0 = tid & 15;
        const int u = us * 16 + ul;
        const float* wi = wA_ih2 + (size_t)u * 768;
        const float* wh = wlds + ul * 388;
        const float br = b_ih2[u] + b_hh2[u];
        const float bz = b_ih2[u + 128] + b_hh2[u + 128];
        const float bxn = b_ih2[u + 256];
        const float bhn = b_hh2[u + 256];
        float4 pregs[8];
        bool pf = false;
        for (int t = 0; t < 1024; ++t) {
            // upstream >= t+1 (skip lanes when prefetched), downstream >= t-3
            pollw(pT, t + dT, aT && (lane >= 8 || !pf), fcT);
            if (pf) stage_write<256>(pregs, hin);
            else    stageX<256>(hin, h1r + (size_t)(t & 3) * 8192);
            __syncthreads();
            float ar[2] = {br, br}, az[2] = {bz, bz};
            float axn[2] = {bxn, bxn}, ahn[2] = {bhn, bhn};
            dot3<2, 256>(wi, hin, b0, ar, az, axn);
            pollw(pM, t, aM, fcM);             // peers (hidden under ih dot)
            if (t > 0) stageX<128>(hprev, h2r + (size_t)((t - 1) & 3) * 4096);
            else       zero32<128>(hprev);
            __syncthreads();
            dot3<2, 128>(wh, hprev, b0, ar, az, ahn);
            // prefetch hin(t+1): cached upstream flag, refresh if stale
            pf = false;
            if (t < 1023) {
                if (aUp && fcT < t + 2) fcT = flag_ld(pT);
                pf = __all(!aUp || fcT >= t + 2);
                if (pf) stage_load<256>(pregs, h1r + (size_t)((t + 1) & 3) * 8192);
            }
            float* hout = h2r + (size_t)(t & 3) * 4096;
            #pragma unroll
            for (int k = 0; k < 2; ++k) {
                int b = b0 + 16 * k;
                float hp = hprev[b * 132 + u];
                float r = sigmoidf_(ar[k]);
                float z = sigmoidf_(az[k]);
                float n = tanhf_(axn[k] + r * ahn[k]);
                hst[b * 20 + ul] = (1.f - z) * n + z * hp;
            }
            __syncthreads();
            ring_store<16, 128>(hout + us * 16, hst);
            asm volatile("s_waitcnt vmcnt(0)" ::: "memory");
            __syncthreads();
            if (tid == 0) flag_st(arr_own + us, t + 1);
        }
    } else if (s == 2) {
        // ---- layer 3: in=128, H=128, 16 units/slice, KB=2 ----
        float* wlds = smem;            // [16][388]
        float* hin = smem + 6208;      // [32][132]
        float* hprev = smem + 10432;   // [32][132]
        float* hst = smem + 14656;     // [32][20]
        {
            const float* srcw = wA_hh3 + (size_t)us * 16 * 384;
            for (int i = tid; i < 6144; i += 256) {
                int uu = i / 384, r = i - uu * 384;
                wlds[uu * 388 + r] = srcw[i];
            }
        }
        __syncthreads();
        const int ul = tid >> 4, b0 = tid & 15;
        const int u = us * 16 + ul;
        const float* wi = wA_ih3 + (size_t)u * 384;
        const float* wh = wlds + ul * 388;
        const float br = b_ih3[u] + b_hh3[u];
        const float bz = b_ih3[u + 128] + b_hh3[u + 128];
        const float bxn = b_ih3[u + 256];
        const float bhn = b_hh3[u + 256];
        float4 pregs[4];
        bool pf = false;
        for (int t = 0; t < 1024; ++t) {
            pollw(pT, t + dT, aT && (lane >= 8 || !pf), fcT);
            if (pf) stage_write<128>(pregs, hin);
            else    stageX<128>(hin, h2r + (size_t)(t & 3) * 4096);
            __syncthreads();
            float ar[2] = {br, br}, az[2] = {bz, bz};
            float axn[2] = {bxn, bxn}, ahn[2] = {bhn, bhn};
            dot3<2, 128>(wi, hin, b0, ar, az, axn);
            pollw(pM, t, aM, fcM);
            if (t > 0) stageX<128>(hprev, h3r + (size_t)((t - 1) & 3) * 4096);
            else       zero32<128>(hprev);
            __syncthreads();
            dot3<2, 128>(wh, hprev, b0, ar, az, ahn);
            pf = false;
            if (t < 1023) {
                if (aUp && fcT < t + 2) fcT = flag_ld(pT);
                pf = __all(!aUp || fcT >= t + 2);
                if (pf) stage_load<128>(pregs, h2r + (size_t)((t + 1) & 3) * 4096);
            }
            float* hout = h3r + (size_t)(t & 3) * 4096;
            #pragma unroll
            for (int k = 0; k < 2; ++k) {
                int b = b0 + 16 * k;
                float hp = hprev[b * 132 + u];
                float r = sigmoidf_(ar[k]);
                float z = sigmoidf_(az[k]);
                float n = tanhf_(axn[k] + r * ahn[k]);
                hst[b * 20 + ul] = (1.f - z) * n + z * hp;
            }
            __syncthreads();
            ring_store<16, 128>(hout + us * 16, hst);
            asm volatile("s_waitcnt vmcnt(0)" ::: "memory");
            __syncthreads();
            if (tid == 0) flag_st(arr_own + us, t + 1);
        }
    } else {
        // ---- layer 4: in=128, H=256, 32 units/slice, KB=4, + projection ----
        float* wlds = smem;            // [32][772]
        float* hin = smem + 24704;     // [32][132]
        float* hprev = smem + 28928;   // [32][260]
        float* hst = smem + 37248;     // [32][36]
        {
            const float* srcw = wA_hh4 + (size_t)us * 32 * 768;
            for (int i = tid; i < 24576; i += 256) {
                int uu = i / 768, r = i - uu * 768;
                wlds[uu * 772 + r] = srcw[i];
            }
        }
        __syncthreads();
        const int ul = tid >> 3, b0 = tid & 7;
        const int u = us * 32 + ul;
        const float* wi = wA_ih4 + (size_t)u * 384;
        const float* wh = wlds + ul * 772;
        const float br = b_ih4[u] + b_hh4[u];
        const float bz = b_ih4[u + 256] + b_hh4[u + 256];
        const float bxn = b_ih4[u + 512];
        const float bhn = b_hh4[u + 512];
        const float wo = w_out[u];
        float4 pregs[4];
        bool pf = false;
        for (int t = 0; t < 1024; ++t) {
            pollw(pT, t + dT, aT && !pf, fcT);   // upstream only (no downstream)
            if (pf) stage_write<128>(pregs, hin);
            else    stageX<128>(hin, h3r + (size_t)(t & 3) * 4096);
            __syncthreads();
            float ar[4], az[4], axn[4], ahn[4];
            #pragma unroll
            for (int k = 0; k < 4; ++k) {
                ar[k] = br; az[k] = bz; axn[k] = bxn; ahn[k] = bhn;
            }
            dot3<4, 128>(wi, hin, b0, ar, az, axn);
            pollw(pM, t, aM, fcM);
            if (t > 0) stageX<256>(hprev, h4r + (size_t)((t - 1) & 3) * 8192);
            else       zero32<256>(hprev);
            __syncthreads();
            dot3<4, 256>(wh, hprev, b0, ar, az, ahn);
            pf = false;
            if (t < 1023) {
                if (aUp && fcT < t + 2) fcT = flag_ld(pT);
                pf = __all(!aUp || fcT >= t + 2);
                if (pf) stage_load<128>(pregs, h3r + (size_t)((t + 1) & 3) * 4096);
            }
            float* hout = h4r + (size_t)(t & 3) * 8192;
            float pk[4];
            #pragma unroll
            for (int k = 0; k < 4; ++k) {
                int b = b0 + 8 * k;
                float hp = hprev[b * 260 + u];
                float r = sigmoidf_(ar[k]);
                float z = sigmoidf_(az[k]);
                float n = tanhf_(axn[k] + r * ahn[k]);
                float hnew = (1.f - z) * n + z * hp;
                hst[b * 36 + ul] = hnew;
                pk[k] = wo * hnew;
            }
            #pragma unroll
            for (int k = 0; k < 4; ++k) {
                pk[k] += __shfl_xor(pk[k], 8, 64);
                pk[k] += __shfl_xor(pk[k], 16, 64);
                pk[k] += __shfl_xor(pk[k], 32, 64);
            }
            if ((tid & 63) < 8) {
                int w = tid >> 6;
                #pragma unroll
                for (int k = 0; k < 4; ++k) wsum[w][k][tid & 7] = pk[k];
            }
            __syncthreads();
            ring_store<32, 256>(hout + us * 32, hst);
            asm volatile("s_waitcnt vmcnt(0)" ::: "memory");
            __syncthreads();
            if (tid == 0) flag_st(arr_own + us, t + 1);
            if (tid < 32) {
                int k = tid >> 3, bb = tid & 7;
                float ssum = wsum[0][k][bb] + wsum[1][k][bb] +
                             wsum[2][k][bb] + wsum[3][k][bb];
                if (us == 0) ssum += b_out[0];
                atomicAdd(out + (size_t)(bg * 32 + bb + 8 * k) * 1024 + t, ssum);
            }
        }
    }
}

extern "C" void kernel_launch(void* const* d_in, const int* in_sizes, int n_in,
                              void* d_out, int out_size, void* d_ws, size_t ws_size,
                              hipStream_t stream) {
    const float* x     = (const float*)d_in[0];
    const float* w_ih1 = (const float*)d_in[1];
    const float* w_hh1 = (const float*)d_in[2];
    const float* b_ih1 = (const float*)d_in[3];
    const float* b_hh1 = (const float*)d_in[4];
    const float* w_ih2 = (const float*)d_in[5];
    const float* w_hh2 = (const float*)d_in[6];
    const float* b_ih2 = (const float*)d_in[7];
    const float* b_hh2 = (const float*)d_in[8];
    const float* w_ih3 = (const float*)d_in[9];
    const float* w_hh3 = (const float*)d_in[10];
    const float* b_ih3 = (const float*)d_in[11];
    const float* b_hh3 = (const float*)d_in[12];
    const float* w_ih4 = (const float*)d_in[13];
    const float* w_hh4 = (const float*)d_in[14];
    const float* b_ih4 = (const float*)d_in[15];
    const float* b_hh4 = (const float*)d_in[16];
    const float* w_out = (const float*)d_in[17];
    const float* b_out = (const float*)d_in[18];

    float* ws = (float*)d_ws;
    float* wA_hh1 = ws;                  // 196608
    float* wA_ih2 = wA_hh1 + 196608;     //  98304
    float* wA_hh2 = wA_ih2 + 98304;      //  49152
    float* wA_ih3 = wA_hh2 + 49152;      //  49152
    float* wA_hh3 = wA_ih3 + 49152;      //  49152
    float* wA_ih4 = wA_hh3 + 49152;      //  98304
    float* wA_hh4 = wA_ih4 + 98304;      // 196608
    float* ex     = wA_hh4 + 196608;     // 786432 (8 bg x 98304)
    int*   flags  = (int*)(ex + 786432); // 8 x 128 ints

    (void)hipMemsetAsync(flags, 0, 1024 * sizeof(int), stream);
    (void)hipMemsetAsync(d_out, 0, 256 * 1024 * sizeof(float), stream);

    prep_k<<<768, 256, 0, stream>>>(w_hh1, wA_hh1, 256, 256);
    prep_k<<<384, 256, 0, stream>>>(w_ih2, wA_ih2, 128, 256);
    prep_k<<<192, 256, 0, stream>>>(w_hh2, wA_hh2, 128, 128);
    prep_k<<<192, 256, 0, stream>>>(w_ih3, wA_ih3, 128, 128);
    prep_k<<<192, 256, 0, stream>>>(w_hh3, wA_hh3, 128, 128);
    prep_k<<<384, 256, 0, stream>>>(w_ih4, wA_ih4, 256, 128);
    prep_k<<<768, 256, 0, stream>>>(w_hh4, wA_hh4, 256, 256);

    // 150KB dynamic LDS (38400 floats): 1 block/CU; grid=256 => co-resident.
    const int dyn_lds = 38400 * (int)sizeof(float);
    (void)hipFuncSetAttribute((const void*)gru_pipe_kernel,
                              hipFuncAttributeMaxDynamicSharedMemorySize, dyn_lds);

    gru_pipe_kernel<<<256, 256, dyn_lds, stream>>>(
        x, w_ih1, b_ih1, b_hh1, b_ih2, b_hh2, b_ih3, b_hh3, b_ih4, b_hh4,
        wA_hh1, wA_ih2, wA_hh2, wA_ih3, wA_hh3, wA_ih4, wA_hh4,
        w_out, b_out, flags, ex, (float*)d_out);
}